// Round 4
// baseline (881.571 us; speedup 1.0000x reference)
//
#include <hip/hip_runtime.h>

#define T_STEPS 256
#define BATCH   128
#define FEAT    1536            // DH * L = 512 * 3
#define NPAIRS  (T_STEPS * BATCH)

// ---------------------------------------------------------------------------
// DPP full-wave (64-lane) sum. Result valid in lane 63. All VALU-pipe.
// ---------------------------------------------------------------------------
template <int CTRL, int RMASK>
__device__ __forceinline__ float dpp_add_step(float v) {
    int m = __builtin_amdgcn_update_dpp(0, __float_as_int(v), CTRL, RMASK, 0xF, true);
    return v + __int_as_float(m);
}

__device__ __forceinline__ float wave_reduce63(float v) {
    v = dpp_add_step<0x111, 0xF>(v);   // row_shr:1
    v = dpp_add_step<0x112, 0xF>(v);   // row_shr:2
    v = dpp_add_step<0x114, 0xF>(v);   // row_shr:4
    v = dpp_add_step<0x118, 0xF>(v);   // row_shr:8  -> lanes 15/31/47/63
    v = dpp_add_step<0x142, 0xA>(v);   // row_bcast:15 into rows 1,3
    v = dpp_add_step<0x143, 0xC>(v);   // row_bcast:31 into rows 2,3
    return v;
}

// 1 - sigmoid(x) = 1/(1 + e^x); inf-safe without clamps (rcp(inf)=0).
__device__ __forceinline__ float one_minus_sig(float x) {
    float e = __builtin_amdgcn_exp2f(x * 1.4426950408889634f);
    return __builtin_amdgcn_rcpf(1.0f + e);
}

// tanh(x) = 1 - 2/(1 + e^{2x}); saturates correctly at +/-inf, no clamps.
__device__ __forceinline__ float tanh_fast(float x) {
    float e = __builtin_amdgcn_exp2f(x * 2.8853900817779268f);
    return fmaf(-2.0f, __builtin_amdgcn_rcpf(1.0f + e), 1.0f);
}

// LDS-only barrier: orders ds_write/ds_read across waves WITHOUT draining
// the outstanding global stores.
__device__ __forceinline__ void barrier_lds_only() {
    asm volatile("s_waitcnt lgkmcnt(0)\n\ts_barrier" ::: "memory");
}

union F2U { float2 f; unsigned long long u; };

// ---------------------------------------------------------------------------
// One kernel, two roles:
//   blocks [0,128)   : PRODUCER for batch b=blockIdx. Wave w computes
//                      X[b][t] = x_t[b,:]·Wi + bi for t in [64w, 64w+64):
//                      24 elem/lane, DPP reduce, lane63 stores 8B (relaxed
//                      agent atomic), release-publishes prog[4b+w] every 4
//                      rows. Producers never wait -> deadlock-free.
//   blocks [128,256) : CONSUMER scan for batch b=blockIdx-128. EXACTLY the
//                      proven X-free scan structure (4 waves, 6 elem/thread,
//                      one lgkm-only barrier/step, fire-and-forget stores).
//                      X(t) arrives as a distance-4 register prefetch of an
//                      8B agent atomic load, guarded by an acquire spin on
//                      prog that only fires at startup/chunk boundaries.
// All 256 blocks co-resident on 256 CUs; the 192MB input read happens on
// producer CUs, fully overlapped with the latency-bound scan chain.
// ---------------------------------------------------------------------------
__global__ __launch_bounds__(256) void rg_cell_kernel(
    const float* __restrict__ inputs,   // (T, B, 1536)
    const float* __restrict__ h0,
    const float* __restrict__ c0,
    const float* __restrict__ Wr, const float* __restrict__ br,
    const float* __restrict__ Wc, const float* __restrict__ bc,
    const float* __restrict__ Wi, const float* __restrict__ bi,
    float* __restrict__ outs,       // (T, B, 1536)
    float* __restrict__ hT,         // (B, 1536)
    float* __restrict__ cT,         // (B, 1536)
    float* __restrict__ Xws,        // (B, T) float2 workspace
    int*   __restrict__ prog)       // (B, 4) per-wave progress counters
{
    const int tid  = threadIdx.x;
    const int wid  = tid >> 6;
    const int lane = tid & 63;

    if (blockIdx.x < BATCH) {
        // =================== PRODUCER ===================
        const int b = blockIdx.x;

        // Wi fragments: lane l takes float4 at float-offset j*256 + l*4
        float4 wiA[6], wiB[6];
#pragma unroll
        for (int j = 0; j < 6; ++j) {
            wiA[j] = *(const float4*)(Wi + j * 256 + lane * 4);
            wiB[j] = *(const float4*)(Wi + FEAT + j * 256 + lane * 4);
        }
        const float bi0 = bi[0], bi1 = bi[1];

        int* pr = prog + 4 * b + wid;
        unsigned long long* Xb =
            (unsigned long long*)((float2*)Xws + (size_t)b * T_STEPS);

#pragma unroll 1
        for (int k = 0; k < 64; ++k) {
            const int t = (wid << 6) + k;
            const float* xp = inputs + ((size_t)t * BATCH + b) * FEAT;
            float4 xv[6];
#pragma unroll
            for (int j = 0; j < 6; ++j)
                xv[j] = *(const float4*)(xp + j * 256 + lane * 4);

            float a0 = 0.0f, a1 = 0.0f;
#pragma unroll
            for (int j = 0; j < 6; ++j) {
                a0 = fmaf(xv[j].x, wiA[j].x, a0);
                a0 = fmaf(xv[j].y, wiA[j].y, a0);
                a0 = fmaf(xv[j].z, wiA[j].z, a0);
                a0 = fmaf(xv[j].w, wiA[j].w, a0);
                a1 = fmaf(xv[j].x, wiB[j].x, a1);
                a1 = fmaf(xv[j].y, wiB[j].y, a1);
                a1 = fmaf(xv[j].z, wiB[j].z, a1);
                a1 = fmaf(xv[j].w, wiB[j].w, a1);
            }
            a0 = wave_reduce63(a0);
            a1 = wave_reduce63(a1);
            if (lane == 63) {
                F2U q; q.f = make_float2(a0 + bi0, a1 + bi1);
                __hip_atomic_store(Xb + t, q.u, __ATOMIC_RELAXED,
                                   __HIP_MEMORY_SCOPE_AGENT);
                if ((k & 3) == 3) {
                    __hip_atomic_store(pr, k + 1, __ATOMIC_RELEASE,
                                       __HIP_MEMORY_SCOPE_AGENT);
                }
            }
        }
        return;
    }

    // =================== CONSUMER (scan) ===================
    const int b = blockIdx.x - BATCH;

    __shared__ float4 red[2][4];    // double-buffered: 4 waves x (Hc,Hh,Cc,Ch)

    const float4 wr0_4 = ((const float4*)Wr)[tid];
    const float4 wr1_4 = ((const float4*)(Wr + FEAT))[tid];
    const float2 wr0_2 = ((const float2*)(Wr + 1024))[tid];
    const float2 wr1_2 = ((const float2*)(Wr + FEAT + 1024))[tid];
    const float4 wc0_4 = ((const float4*)Wc)[tid];
    const float4 wc1_4 = ((const float4*)(Wc + FEAT))[tid];
    const float2 wc0_2 = ((const float2*)(Wc + 1024))[tid];
    const float2 wc1_2 = ((const float2*)(Wc + FEAT + 1024))[tid];
    const float br0 = br[0], br1 = br[1];
    const float bc0 = bc[0], bc1 = bc[1];

    const float* h0b = h0 + (size_t)b * FEAT;
    const float* c0b = c0 + (size_t)b * FEAT;
    float4 h4 = ((const float4*)h0b)[tid];
    float2 h2 = ((const float2*)(h0b + 1024))[tid];
    float4 c4 = ((const float4*)c0b)[tid];
    float2 c2 = ((const float2*)(c0b + 1024))[tid];

    float* op = outs + (size_t)b * FEAT;
    const size_t OSTRIDE = (size_t)BATCH * FEAT;

    const unsigned long long* Xb =
        (const unsigned long long*)((const float2*)Xws + (size_t)b * T_STEPS);
    int* pr0 = prog + 4 * b;

    // progress tracking (thread-uniform scalars)
    int cur_chunk = 0;
    int known = 0;

    // Prologue: wait for X[0..3] (chunk 0), then fill the 4 rotating slots.
    while (known < 4) {
        known = __hip_atomic_load(pr0, __ATOMIC_ACQUIRE, __HIP_MEMORY_SCOPE_AGENT);
    }
    F2U q0, q1, q2, q3;
    q0.u = __hip_atomic_load(Xb + 0, __ATOMIC_RELAXED, __HIP_MEMORY_SCOPE_AGENT);
    q1.u = __hip_atomic_load(Xb + 1, __ATOMIC_RELAXED, __HIP_MEMORY_SCOPE_AGENT);
    q2.u = __hip_atomic_load(Xb + 2, __ATOMIC_RELAXED, __HIP_MEMORY_SCOPE_AGENT);
    q3.u = __hip_atomic_load(Xb + 3, __ATOMIC_RELAXED, __HIP_MEMORY_SCOPE_AGENT);
    float2 xs0 = q0.f, xs1 = q1.f, xs2 = q2.f, xs3 = q3.f;

    // step t: consume xslot (holds X(t), bias included); post-barrier,
    // prefetch X(t+4) into the same slot (guarded by acquire on prog).
    auto step = [&](float4* buf, int t, float2& xslot) {
        const float2 Xv = xslot;

        float pHc = h4.x * wr0_4.x + h4.y * wr0_4.y + h4.z * wr0_4.z + h4.w * wr0_4.w
                  + h2.x * wr0_2.x + h2.y * wr0_2.y;
        float pHh = h4.x * wr1_4.x + h4.y * wr1_4.y + h4.z * wr1_4.z + h4.w * wr1_4.w
                  + h2.x * wr1_2.x + h2.y * wr1_2.y;
        float pCc = c4.x * wc0_4.x + c4.y * wc0_4.y + c4.z * wc0_4.z + c4.w * wc0_4.w
                  + c2.x * wc0_2.x + c2.y * wc0_2.y;
        float pCh = c4.x * wc1_4.x + c4.y * wc1_4.y + c4.z * wc1_4.z + c4.w * wc1_4.w
                  + c2.x * wc1_2.x + c2.y * wc1_2.y;

        pHc = wave_reduce63(pHc);
        pHh = wave_reduce63(pHh);
        pCc = wave_reduce63(pCc);
        pCh = wave_reduce63(pCh);

        if (lane == 63) {
            buf[wid] = make_float4(pHc, pHh, pCc, pCh);
        }
        barrier_lds_only();
        const float4 r0 = buf[0];
        const float4 r1 = buf[1];
        const float4 r2 = buf[2];
        const float4 r3 = buf[3];

        // ---- X prefetch for t+4 (off the recurrence critical path) ----
        const int tq = t + 4;
        if (tq < T_STEPS) {
            const int cq = tq >> 6;
            const int iq = tq & 63;
            if (cq != cur_chunk) { cur_chunk = cq; known = 0; }
            if (known <= iq) {
                do {
                    known = __hip_atomic_load(pr0 + cq, __ATOMIC_ACQUIRE,
                                              __HIP_MEMORY_SCOPE_AGENT);
                } while (known <= iq);
            }
            F2U qv;
            qv.u = __hip_atomic_load(Xb + tq, __ATOMIC_RELAXED,
                                     __HIP_MEMORY_SCOPE_AGENT);
            xslot = qv.f;
        }

        const float Hc = r0.x + r1.x + r2.x + r3.x + br0;
        const float Hh = r0.y + r1.y + r2.y + r3.y + br1;
        const float Cc = r0.z + r1.z + r2.z + r3.z + bc0;
        const float Ch = r0.w + r1.w + r2.w + r3.w + bc1;
        const float Xc = Xv.x;      // bias folded in by producer
        const float Xh = Xv.y;

        // gh = (1-sig(Ch))*Xh + (1-sig(Hh))*h ; gc = (1-sig(Hc))*Xc + (1-sig(Cc))*c
        const float Ah = one_minus_sig(Ch) * Xh;
        const float Sh = one_minus_sig(Hh);
        const float Ac = one_minus_sig(Hc) * Xc;
        const float Sc = one_minus_sig(Cc);

        h4.x = tanh_fast(fmaf(Sh, h4.x, Ah));
        h4.y = tanh_fast(fmaf(Sh, h4.y, Ah));
        h4.z = tanh_fast(fmaf(Sh, h4.z, Ah));
        h4.w = tanh_fast(fmaf(Sh, h4.w, Ah));
        h2.x = tanh_fast(fmaf(Sh, h2.x, Ah));
        h2.y = tanh_fast(fmaf(Sh, h2.y, Ah));

        c4.x = tanh_fast(fmaf(Sc, c4.x, Ac));
        c4.y = tanh_fast(fmaf(Sc, c4.y, Ac));
        c4.z = tanh_fast(fmaf(Sc, c4.z, Ac));
        c4.w = tanh_fast(fmaf(Sc, c4.w, Ac));
        c2.x = tanh_fast(fmaf(Sc, c2.x, Ac));
        c2.y = tanh_fast(fmaf(Sc, c2.y, Ac));

        // outs[t, b, :] = ht (fire-and-forget; never drained inside the loop)
        ((float4*)op)[tid]          = h4;
        ((float2*)(op + 1024))[tid] = h2;
        op += OSTRIDE;
        // Double-buffer safety with ONE barrier/step: a wave's re-write of
        // buf (step t+2) happens after barrier t+1, which every wave reaches
        // only after its step-t read of this buffer.
    };

#pragma unroll 1
    for (int t = 0; t < T_STEPS; t += 4) {
        step(red[0], t,     xs0);
        step(red[1], t + 1, xs1);
        step(red[0], t + 2, xs2);
        step(red[1], t + 3, xs3);
    }

    float* hp = hT + (size_t)b * FEAT;
    ((float4*)hp)[tid]          = h4;
    ((float2*)(hp + 1024))[tid] = h2;
    float* cp = cT + (size_t)b * FEAT;
    ((float4*)cp)[tid]          = c4;
    ((float2*)(cp + 1024))[tid] = c2;
}

extern "C" void kernel_launch(void* const* d_in, const int* in_sizes, int n_in,
                              void* d_out, int out_size, void* d_ws, size_t ws_size,
                              hipStream_t stream) {
    const float* inputs = (const float*)d_in[0];
    const float* h0     = (const float*)d_in[1];
    const float* c0     = (const float*)d_in[2];
    const float* Wr     = (const float*)d_in[3];
    const float* br     = (const float*)d_in[4];
    const float* Wc     = (const float*)d_in[5];
    const float* bc     = (const float*)d_in[6];
    const float* Wi     = (const float*)d_in[7];
    const float* bi     = (const float*)d_in[8];

    float* out  = (float*)d_out;
    float* outs = out;                                        // (T,B,1536)
    float* hT   = out + (size_t)NPAIRS * FEAT;                // (B,1536)
    float* cT   = hT + (size_t)BATCH * FEAT;                  // (B,1536)

    float* X    = (float*)d_ws;                               // 256 KiB (B,T) float2
    int*   prog = (int*)((char*)d_ws + 256 * 1024);           // 2 KiB (B,4)

    // Reset progress flags every launch (workspace may be re-poisoned).
    hipMemsetAsync(prog, 0, BATCH * 4 * sizeof(int), stream);

    rg_cell_kernel<<<2 * BATCH, 256, 0, stream>>>(inputs, h0, c0, Wr, br,
                                                  Wc, bc, Wi, bi,
                                                  outs, hT, cT, X, prog);
}

// Round 5
// 395.548 us; speedup vs baseline: 2.2287x; 2.2287x over previous
//
#include <hip/hip_runtime.h>

#define T_STEPS 256
#define BATCH   128
#define FEAT    1536            // DH * L = 512 * 3
#define NPAIRS  (T_STEPS * BATCH)

// ---------------------------------------------------------------------------
// DPP full-wave (64-lane) sum. Result valid in lane 63. All VALU-pipe.
// ---------------------------------------------------------------------------
template <int CTRL, int RMASK>
__device__ __forceinline__ float dpp_add_step(float v) {
    int m = __builtin_amdgcn_update_dpp(0, __float_as_int(v), CTRL, RMASK, 0xF, true);
    return v + __int_as_float(m);
}

__device__ __forceinline__ float wave_reduce63(float v) {
    v = dpp_add_step<0x111, 0xF>(v);   // row_shr:1
    v = dpp_add_step<0x112, 0xF>(v);   // row_shr:2
    v = dpp_add_step<0x114, 0xF>(v);   // row_shr:4
    v = dpp_add_step<0x118, 0xF>(v);   // row_shr:8  -> lanes 15/31/47/63
    v = dpp_add_step<0x142, 0xA>(v);   // row_bcast:15 into rows 1,3
    v = dpp_add_step<0x143, 0xC>(v);   // row_bcast:31 into rows 2,3
    return v;
}

// 1 - sigmoid(x) = 1/(1 + e^x); inf-safe without clamps (rcp(inf)=0).
__device__ __forceinline__ float one_minus_sig(float x) {
    float e = __builtin_amdgcn_exp2f(x * 1.4426950408889634f);
    return __builtin_amdgcn_rcpf(1.0f + e);
}

// tanh(x) = 1 - 2/(1 + e^{2x}); saturates correctly at +/-inf, no clamps.
__device__ __forceinline__ float tanh_fast(float x) {
    float e = __builtin_amdgcn_exp2f(x * 2.8853900817779268f);
    return fmaf(-2.0f, __builtin_amdgcn_rcpf(1.0f + e), 1.0f);
}

// LDS-only barrier: orders ds_write/ds_read across waves WITHOUT draining
// the outstanding global stores (__syncthreads would emit s_waitcnt vmcnt(0)
// before s_barrier, putting HBM store latency on the serial scan path).
__device__ __forceinline__ void barrier_lds_only() {
    asm volatile("s_waitcnt lgkmcnt(0)\n\ts_barrier" ::: "memory");
}

// ---------------------------------------------------------------------------
// Fused scan, round 5: per-wave whole-row X ownership (X cost amortized /4).
//   - Each wave computes ONE FULL X row (24 elem/lane, wave-local dot, same
//     partial order as the round-4 producer which passed verification) once
//     per 4-step group: at group-start step t, wave w computes row t+8+w and
//     publishes the finished scalar pair (bias folded) to a 16-deep LDS ring.
//   - x-row registers (24 floats/lane/wave) are refilled right after use with
//     the row needed 4 steps later -> ~3us of slack vs ~1us HBM latency; no
//     memory wait ever lands on the recurrence chain.
//   - Consume side is now ONE 8B LDS broadcast read (slot t&15) instead of
//     4x8B partial reads + 3 adds + bias.
//   - Ring safety: write slots (t+8..t+11)&15 in interval t never alias the
//     slots (t..t+3)&15 read in intervals t..t+3; reuse period 16 steps with
//     >=4 barriers between write and rewrite.
//   - h/c recurrence structure and numerics identical to the proven scan.
// ---------------------------------------------------------------------------
__global__ __launch_bounds__(256) void scan_fused_kernel(
    const float* __restrict__ inputs,   // (T, B, 1536)
    const float* __restrict__ h0,
    const float* __restrict__ c0,
    const float* __restrict__ Wr, const float* __restrict__ br,
    const float* __restrict__ Wc, const float* __restrict__ bc,
    const float* __restrict__ Wi, const float* __restrict__ bi,
    float* __restrict__ outs,       // (T, B, 1536)
    float* __restrict__ hT,         // (B, 1536)
    float* __restrict__ cT)         // (B, 1536)
{
    const int b    = blockIdx.x;
    const int tid  = threadIdx.x;
    const int wid  = tid >> 6;
    const int lane = tid & 63;

    __shared__ float4 red[2][4];    // double-buffered: 4 waves x (Hc,Hh,Cc,Ch)
    __shared__ float2 XR[16];       // finished X values ring (bias folded)

    const float4 wr0_4 = ((const float4*)Wr)[tid];
    const float4 wr1_4 = ((const float4*)(Wr + FEAT))[tid];
    const float2 wr0_2 = ((const float2*)(Wr + 1024))[tid];
    const float2 wr1_2 = ((const float2*)(Wr + FEAT + 1024))[tid];
    const float4 wc0_4 = ((const float4*)Wc)[tid];
    const float4 wc1_4 = ((const float4*)(Wc + FEAT))[tid];
    const float2 wc0_2 = ((const float2*)(Wc + 1024))[tid];
    const float2 wc1_2 = ((const float2*)(Wc + FEAT + 1024))[tid];
    const float br0 = br[0], br1 = br[1];
    const float bc0 = bc[0], bc1 = bc[1];
    const float bi0 = bi[0], bi1 = bi[1];

    // Wi fragments for the per-wave whole-row dot: lane l covers float4 at
    // float-offset j*256 + l*4, j = 0..5 (coalesced 1KB chunks).
    float4 wiA[6], wiB[6];
#pragma unroll
    for (int j = 0; j < 6; ++j) {
        wiA[j] = *(const float4*)(Wi + j * 256 + lane * 4);
        wiB[j] = *(const float4*)(Wi + FEAT + j * 256 + lane * 4);
    }

    const float* h0b = h0 + (size_t)b * FEAT;
    const float* c0b = c0 + (size_t)b * FEAT;
    float4 h4 = ((const float4*)h0b)[tid];
    float2 h2 = ((const float2*)(h0b + 1024))[tid];
    float4 c4 = ((const float4*)c0b)[tid];
    float2 c2 = ((const float2*)(c0b + 1024))[tid];

    // Full X-row dot for row t, entirely within this wave; publishes to ring.
    auto compute_row = [&](int t, const float4* xv) {
        float a0 = 0.0f, a1 = 0.0f;
#pragma unroll
        for (int j = 0; j < 6; ++j) {
            a0 = fmaf(xv[j].x, wiA[j].x, a0);
            a0 = fmaf(xv[j].y, wiA[j].y, a0);
            a0 = fmaf(xv[j].z, wiA[j].z, a0);
            a0 = fmaf(xv[j].w, wiA[j].w, a0);
            a1 = fmaf(xv[j].x, wiB[j].x, a1);
            a1 = fmaf(xv[j].y, wiB[j].y, a1);
            a1 = fmaf(xv[j].z, wiB[j].z, a1);
            a1 = fmaf(xv[j].w, wiB[j].w, a1);
        }
        a0 = wave_reduce63(a0);
        a1 = wave_reduce63(a1);
        if (lane == 63) {
            XR[t & 15] = make_float2(a0 + bi0, a1 + bi1);
        }
    };

    auto load_row = [&](int t, float4* xv) {
        const float* xp = inputs + ((size_t)t * BATCH + b) * FEAT;
#pragma unroll
        for (int j = 0; j < 6; ++j)
            xv[j] = *(const float4*)(xp + j * 256 + lane * 4);
    };

    // ---- Prologue: wave w computes rows w and 4+w, preloads row 8+w ----
    float4 xreg[6];
    load_row(wid, xreg);
    compute_row(wid, xreg);
    load_row(4 + wid, xreg);
    compute_row(4 + wid, xreg);
    load_row(8 + wid, xreg);

    float* op = outs + (size_t)b * FEAT;
    const size_t OSTRIDE = (size_t)BATCH * FEAT;

    __syncthreads();   // ring slots 0..7 visible (one-time full barrier)

    // Shared step body. DO_X: group-start step -> this wave computes row
    // t+8+wid from xreg and refills xreg with row t+12+wid.
    auto step = [&](float4* buf, int t, bool DO_X) {
        float pHc = h4.x * wr0_4.x + h4.y * wr0_4.y + h4.z * wr0_4.z + h4.w * wr0_4.w
                  + h2.x * wr0_2.x + h2.y * wr0_2.y;
        float pHh = h4.x * wr1_4.x + h4.y * wr1_4.y + h4.z * wr1_4.z + h4.w * wr1_4.w
                  + h2.x * wr1_2.x + h2.y * wr1_2.y;
        float pCc = c4.x * wc0_4.x + c4.y * wc0_4.y + c4.z * wc0_4.z + c4.w * wc0_4.w
                  + c2.x * wc0_2.x + c2.y * wc0_2.y;
        float pCh = c4.x * wc1_4.x + c4.y * wc1_4.y + c4.z * wc1_4.z + c4.w * wc1_4.w
                  + c2.x * wc1_2.x + c2.y * wc1_2.y;

        pHc = wave_reduce63(pHc);
        pHh = wave_reduce63(pHh);
        pCc = wave_reduce63(pCc);
        pCh = wave_reduce63(pCh);

        if (lane == 63) {
            buf[wid] = make_float4(pHc, pHh, pCc, pCh);
        }
        barrier_lds_only();
        const float4 r0 = buf[0];
        const float4 r1 = buf[1];
        const float4 r2 = buf[2];
        const float4 r3 = buf[3];
        const float2 Xv = XR[t & 15];   // finished value, bias included

        if (DO_X) {
            // X pipeline: compute row t+8+wid (needed >=8 steps later is not
            // required -- read happens at step t+8+wid, ordered by barriers),
            // then refill xreg with row t+12+wid (4 steps of load slack).
            if (t + 8 < T_STEPS) {
                compute_row(t + 8 + wid, xreg);
            }
            if (t + 12 < T_STEPS) {
                load_row(t + 12 + wid, xreg);
            }
        }

        const float Hc = r0.x + r1.x + r2.x + r3.x + br0;
        const float Hh = r0.y + r1.y + r2.y + r3.y + br1;
        const float Cc = r0.z + r1.z + r2.z + r3.z + bc0;
        const float Ch = r0.w + r1.w + r2.w + r3.w + bc1;
        const float Xc = Xv.x;
        const float Xh = Xv.y;

        // gh = (1-sig(Ch))*Xh + (1-sig(Hh))*h ; gc = (1-sig(Hc))*Xc + (1-sig(Cc))*c
        const float Ah = one_minus_sig(Ch) * Xh;
        const float Sh = one_minus_sig(Hh);
        const float Ac = one_minus_sig(Hc) * Xc;
        const float Sc = one_minus_sig(Cc);

        h4.x = tanh_fast(fmaf(Sh, h4.x, Ah));
        h4.y = tanh_fast(fmaf(Sh, h4.y, Ah));
        h4.z = tanh_fast(fmaf(Sh, h4.z, Ah));
        h4.w = tanh_fast(fmaf(Sh, h4.w, Ah));
        h2.x = tanh_fast(fmaf(Sh, h2.x, Ah));
        h2.y = tanh_fast(fmaf(Sh, h2.y, Ah));

        c4.x = tanh_fast(fmaf(Sc, c4.x, Ac));
        c4.y = tanh_fast(fmaf(Sc, c4.y, Ac));
        c4.z = tanh_fast(fmaf(Sc, c4.z, Ac));
        c4.w = tanh_fast(fmaf(Sc, c4.w, Ac));
        c2.x = tanh_fast(fmaf(Sc, c2.x, Ac));
        c2.y = tanh_fast(fmaf(Sc, c2.y, Ac));

        // outs[t, b, :] = ht (fire-and-forget; never drained inside the loop)
        ((float4*)op)[tid]          = h4;
        ((float2*)(op + 1024))[tid] = h2;
        op += OSTRIDE;
        // Double-buffer safety with ONE barrier/step: a wave's re-write of
        // buf (step t+2) happens after barrier t+1, which every wave reaches
        // only after its step-t read of this buffer.
    };

#pragma unroll 1
    for (int t = 0; t < T_STEPS; t += 4) {
        step(red[0], t,     true);
        step(red[1], t + 1, false);
        step(red[0], t + 2, false);
        step(red[1], t + 3, false);
    }

    float* hp = hT + (size_t)b * FEAT;
    ((float4*)hp)[tid]          = h4;
    ((float2*)(hp + 1024))[tid] = h2;
    float* cp = cT + (size_t)b * FEAT;
    ((float4*)cp)[tid]          = c4;
    ((float2*)(cp + 1024))[tid] = c2;
}

extern "C" void kernel_launch(void* const* d_in, const int* in_sizes, int n_in,
                              void* d_out, int out_size, void* d_ws, size_t ws_size,
                              hipStream_t stream) {
    const float* inputs = (const float*)d_in[0];
    const float* h0     = (const float*)d_in[1];
    const float* c0     = (const float*)d_in[2];
    const float* Wr     = (const float*)d_in[3];
    const float* br     = (const float*)d_in[4];
    const float* Wc     = (const float*)d_in[5];
    const float* bc     = (const float*)d_in[6];
    const float* Wi     = (const float*)d_in[7];
    const float* bi     = (const float*)d_in[8];

    float* out  = (float*)d_out;
    float* outs = out;                                        // (T,B,1536)
    float* hT   = out + (size_t)NPAIRS * FEAT;                // (B,1536)
    float* cT   = hT + (size_t)BATCH * FEAT;                  // (B,1536)

    scan_fused_kernel<<<BATCH, 256, 0, stream>>>(inputs, h0, c0, Wr, br,
                                                 Wc, bc, Wi, bi,
                                                 outs, hT, cT);
}